// Round 4
// baseline (233.485 us; speedup 1.0000x reference)
//
#include <hip/hip_runtime.h>

#define NB   64
#define NT   256
#define NI   512
#define NO   512
#define NOBS 128
#define ETA  0.01f
#define THREADS 256   // 4 waves/block, 2 rows/wave -> 8 rows/block, 16 blocks per batch
#define JPB  8

// one stage of a DPP-based reduction (VALU pipe, no LDS crossbar);
// ctrl/rmask must be compile-time constants for the builtin.
template <int CTRL, int RMASK>
__device__ __forceinline__ float dpp_add(float v) {
    return v + __int_as_float(__builtin_amdgcn_update_dpp(
        0, __float_as_int(v), CTRL, RMASK, 0xf, true));
}

__device__ __forceinline__ void wave_reduce2(float& a, float& b) {
    a = dpp_add<0x111, 0xf>(a);  b = dpp_add<0x111, 0xf>(b);  // row_shr:1
    a = dpp_add<0x112, 0xf>(a);  b = dpp_add<0x112, 0xf>(b);  // row_shr:2
    a = dpp_add<0x114, 0xf>(a);  b = dpp_add<0x114, 0xf>(b);  // row_shr:4
    a = dpp_add<0x118, 0xf>(a);  b = dpp_add<0x118, 0xf>(b);  // row_shr:8
    a = dpp_add<0x142, 0xa>(a);  b = dpp_add<0x142, 0xa>(b);  // row_bcast:15
    a = dpp_add<0x143, 0xc>(a);  b = dpp_add<0x143, 0xc>(b);  // row_bcast:31
    a = __int_as_float(__builtin_amdgcn_readlane(__float_as_int(a), 63));
    b = __int_as_float(__builtin_amdgcn_readlane(__float_as_int(b), 63));
}

__device__ __forceinline__ void do_step(const float4 xa, const float4 xc,
                                        float4& w0a, float4& w0b,
                                        float4& w1a, float4& w1b,
                                        float* op, int lane)
{
    float p0 = w0a.x * xa.x, q0 = w0a.y * xa.y;
    p0 = fmaf(w0a.z, xa.z, p0); q0 = fmaf(w0a.w, xa.w, q0);
    p0 = fmaf(w0b.x, xc.x, p0); q0 = fmaf(w0b.y, xc.y, q0);
    p0 = fmaf(w0b.z, xc.z, p0); q0 = fmaf(w0b.w, xc.w, q0);
    float p1 = w1a.x * xa.x, q1 = w1a.y * xa.y;
    p1 = fmaf(w1a.z, xa.z, p1); q1 = fmaf(w1a.w, xa.w, q1);
    p1 = fmaf(w1b.x, xc.x, p1); q1 = fmaf(w1b.y, xc.y, q1);
    p1 = fmaf(w1b.z, xc.z, p1); q1 = fmaf(w1b.w, xc.w, q1);

    float s0 = p0 + q0, s1 = p1 + q1;
    wave_reduce2(s0, s1);

    const float y0 = __builtin_amdgcn_rcpf(1.f + __expf(-s0));
    const float y1 = __builtin_amdgcn_rcpf(1.f + __expf(-s1));
    if (lane == 0) *(float2*)op = make_float2(y0, y1);

    const float e0 = ETA * y0, e1 = ETA * y1;
    w0a.x = fmaf(e0, xa.x, w0a.x); w0a.y = fmaf(e0, xa.y, w0a.y);
    w0a.z = fmaf(e0, xa.z, w0a.z); w0a.w = fmaf(e0, xa.w, w0a.w);
    w0b.x = fmaf(e0, xc.x, w0b.x); w0b.y = fmaf(e0, xc.y, w0b.y);
    w0b.z = fmaf(e0, xc.z, w0b.z); w0b.w = fmaf(e0, xc.w, w0b.w);
    w1a.x = fmaf(e1, xa.x, w1a.x); w1a.y = fmaf(e1, xa.y, w1a.y);
    w1a.z = fmaf(e1, xa.z, w1a.z); w1a.w = fmaf(e1, xa.w, w1a.w);
    w1b.x = fmaf(e1, xc.x, w1b.x); w1b.y = fmaf(e1, xc.y, w1b.y);
    w1b.z = fmaf(e1, xc.z, w1b.z); w1b.w = fmaf(e1, xc.w, w1b.w);
}

__global__ __launch_bounds__(THREADS, 4)
void circuit_kernel(const float* __restrict__ X,
                    const float* __restrict__ Wi,
                    const int*   __restrict__ obs,
                    float*       __restrict__ out)
{
    const int tid  = threadIdx.x;
    const int lane = tid & 63;
    const int wv   = tid >> 6;                 // 0..3
    // XCD swizzle: blocks of the same batch b are 64 apart -> same XCD (%8),
    // so one XCD's L2 caches X[b] for all 16 blocks of that batch.
    const int b    = blockIdx.x & 63;
    const int jblk = blockIdx.x >> 6;          // 0..15
    const int j0   = jblk * JPB + wv * 2;
    const int o0   = obs[j0];
    const int o1   = obs[j0 + 1];

    // lane owns x/w elements {lane*4+k} and {256+lane*4+k}
    const float* r0 = Wi + ((size_t)b * NO + o0) * NI;
    const float* r1 = Wi + ((size_t)b * NO + o1) * NI;
    float4 w0a = ((const float4*)r0)[lane];
    float4 w0b = ((const float4*)(r0 + 256))[lane];
    float4 w1a = ((const float4*)r1)[lane];
    float4 w1b = ((const float4*)(r1 + 256))[lane];

    const float4* xrow = (const float4*)(X + (size_t)b * NT * NI); // 128 float4 per t
    float* ob = out + (size_t)b * NT * NOBS + j0;

    // software prefetch, depth 2 steps
    float4 xa0 = xrow[lane],       xc0 = xrow[64 + lane];
    float4 xa1 = xrow[128 + lane], xc1 = xrow[192 + lane];

    for (int t = 0; t < NT; t += 2) {
        const int t2 = (t + 2 < NT) ? t + 2 : t;
        float4 xa2 = xrow[t2 * 128 + lane];
        float4 xc2 = xrow[t2 * 128 + 64 + lane];
        do_step(xa0, xc0, w0a, w0b, w1a, w1b, ob + (size_t)t * NOBS, lane);

        const int t3 = (t + 3 < NT) ? t + 3 : t;
        float4 xa3 = xrow[t3 * 128 + lane];
        float4 xc3 = xrow[t3 * 128 + 64 + lane];
        do_step(xa1, xc1, w0a, w0b, w1a, w1b, ob + (size_t)(t + 1) * NOBS, lane);

        xa0 = xa2; xc0 = xc2; xa1 = xa3; xc1 = xc3;
    }
}

extern "C" void kernel_launch(void* const* d_in, const int* in_sizes, int n_in,
                              void* d_out, int out_size, void* d_ws, size_t ws_size,
                              hipStream_t stream)
{
    const float* X   = (const float*)d_in[0];
    const float* Wi  = (const float*)d_in[1];
    const int*   obs = (const int*)d_in[2];
    float*       out = (float*)d_out;

    hipLaunchKernelGGL(circuit_kernel, dim3(NB * (NOBS / JPB)), dim3(THREADS),
                       0, stream, X, Wi, obs, out);
}